// Round 5
// baseline (914.591 us; speedup 1.0000x reference)
//
#include <hip/hip_runtime.h>

#define INDIM 128
#define HID 256
#define NCLS 16
#define NGRAPH 64
#define CHUNK 8192

typedef __bf16 bf16_t;
typedef bf16_t bf16x8 __attribute__((ext_vector_type(8)));
typedef float f32x4 __attribute__((ext_vector_type(4)));

__device__ __forceinline__ float bfu_lo(unsigned v) {
    union { unsigned i; float f; } u; u.i = v << 16; return u.f;
}
__device__ __forceinline__ float bfu_hi(unsigned v) {
    union { unsigned i; float f; } u; u.i = v & 0xffff0000u; return u.f;
}
__device__ __forceinline__ unsigned short f2bf(float f) {  // RNE
    union { float f; unsigned i; } u; u.f = f;
    unsigned b = u.i;
    return (unsigned short)((b + 0x7fffu + ((b >> 16) & 1u)) >> 16);
}

// ---------------- CSR build ----------------
__global__ void hist_kernel(const int* __restrict__ dst, int* __restrict__ deg, int E) {
    int e = blockIdx.x * blockDim.x + threadIdx.x;
    if (e < E) atomicAdd(&deg[dst[e]], 1);
}

__global__ void scan1_kernel(const int* __restrict__ deg, int* __restrict__ bsum, int n) {
    __shared__ int s[256];
    int t = threadIdx.x;
    int i = blockIdx.x * 256 + t;
    s[t] = (i < n) ? deg[i] : 0;
    __syncthreads();
    for (int off = 128; off > 0; off >>= 1) {
        if (t < off) s[t] += s[t + off];
        __syncthreads();
    }
    if (t == 0) bsum[blockIdx.x] = s[0];
}

__global__ void scan2_kernel(int* bsum, int nb) {  // single block, nb <= 1024
    __shared__ int s[1024];
    int t = threadIdx.x;
    int v = (t < nb) ? bsum[t] : 0;
    s[t] = v;
    __syncthreads();
    for (int off = 1; off < 1024; off <<= 1) {
        int u = (t >= off) ? s[t - off] : 0;
        __syncthreads();
        s[t] += u;
        __syncthreads();
    }
    if (t < nb) bsum[t] = s[t] - v;  // exclusive
}

__global__ void scan3_kernel(const int* __restrict__ deg, const int* __restrict__ bsum,
                             int* __restrict__ offs, int n) {
    __shared__ int s[256];
    int t = threadIdx.x;
    int i = blockIdx.x * 256 + t;
    int v = (i < n) ? deg[i] : 0;
    s[t] = v;
    __syncthreads();
    for (int off = 1; off < 256; off <<= 1) {
        int u = (t >= off) ? s[t - off] : 0;
        __syncthreads();
        s[t] += u;
        __syncthreads();
    }
    if (i < n) offs[i] = s[t] - v + bsum[blockIdx.x];
}

// ---------------- two-phase locality-aware edge sort ----------------
__global__ void initcur_kernel(const int* __restrict__ offs, int* __restrict__ gcur, int nbuck) {
    int t = blockIdx.x * blockDim.x + threadIdx.x;
    if (t < nbuck) gcur[t] = offs[t << 8];
}

__global__ __launch_bounds__(256) void binA_kernel(const int* __restrict__ src,
                                                   const int* __restrict__ dst,
                                                   int* __restrict__ gcur,
                                                   unsigned* __restrict__ tmp,
                                                   int E, int nbuck) {
    __shared__ int hist[512];
    __shared__ int base[512];
    int t = threadIdx.x;
    int e0 = blockIdx.x * CHUNK;
    int e1 = min(e0 + CHUNK, E);
    for (int i = t; i < nbuck; i += 256) hist[i] = 0;
    __syncthreads();
    for (int e = e0 + t; e < e1; e += 256) atomicAdd(&hist[dst[e] >> 8], 1);
    __syncthreads();
    for (int i = t; i < nbuck; i += 256) {
        int c = hist[i];
        base[i] = (c > 0) ? atomicAdd(&gcur[i], c) : 0;
    }
    __syncthreads();
    for (int e = e0 + t; e < e1; e += 256) {
        int d = dst[e];
        int p = atomicAdd(&base[d >> 8], 1);
        tmp[p] = ((unsigned)(d & 255) << 17) | (unsigned)src[e];  // src < 2^17
    }
}

__global__ __launch_bounds__(256) void binB_kernel(const unsigned* __restrict__ tmp,
                                                   const int* __restrict__ offs,
                                                   int* __restrict__ srclist, int E, int n) {
    __shared__ int cur[256];
    int b = blockIdx.x;
    int node0 = b << 8;
    int nnodes = min(256, n - node0);
    int t = threadIdx.x;
    if (t < nnodes) cur[t] = offs[node0 + t];
    __syncthreads();
    int ebeg = offs[node0];
    int eend = (node0 + 256 < n) ? offs[node0 + 256] : E;
    for (int e = ebeg + t; e < eend; e += 256) {
        unsigned v = tmp[e];
        int p = atomicAdd(&cur[v >> 17], 1);
        srclist[p] = (int)(v & 0x1FFFFu);
    }
}

// ---------------- casts ----------------
__global__ void cast_x_kernel(const float* __restrict__ x, unsigned short* __restrict__ xb,
                              int total4) {
    int idx = blockIdx.x * blockDim.x + threadIdx.x;
    if (idx >= total4) return;
    int i4 = idx * 4;
    float4 v = *(const float4*)(x + i4);
    *(ushort4*)(xb + i4) = make_ushort4(f2bf(v.x), f2bf(v.y), f2bf(v.z), f2bf(v.w));
}

// Bt1[n*256 + k] = bf16( k<128 ? W1l[k][n] : W1r[k-128][n] )
__global__ void wcast1_kernel(const float* __restrict__ Wl, const float* __restrict__ Wr,
                              unsigned short* __restrict__ Bt) {
    int idx = blockIdx.x * blockDim.x + threadIdx.x;  // 65536
    int n = idx >> 8, k = idx & 255;
    float v = (k < 128) ? Wl[(size_t)k * 256 + n] : Wr[(size_t)(k - 128) * 256 + n];
    Bt[(size_t)n * 256 + k] = f2bf(v);
}

// Bt2[n*512 + k] = bf16( k<256 ? W2l[k][n] : W2r[k-256][n] )
__global__ void wcast2_kernel(const float* __restrict__ Wl, const float* __restrict__ Wr,
                              unsigned short* __restrict__ Bt) {
    int idx = blockIdx.x * blockDim.x + threadIdx.x;  // 131072
    int n = idx >> 9, k = idx & 511;
    float v = (k < 256) ? Wl[(size_t)k * 256 + n] : Wr[(size_t)(k - 256) * 256 + n];
    Bt[(size_t)n * 512 + k] = f2bf(v);
}

// ================= fused SAGE layer 1: mean-gather (LDS) + dual MFMA GEMM =================
// Block = 64 nodes, 4 waves. Phase 1: wave w gathers mean of x over neighbors for nodes
// w*16..w*16+15 straight into a padded LDS tile (never hits global). Phase 2:
// H = relu([mean | root] @ [Wl;Wr] + b) with A1 = LDS tile, A2 = root rows from global.
// LDS pad +8 bf16: row stride 272 B = 68 dwords = 4 mod 32 -> 2-way bank aliasing (free),
// 16B-aligned for ds_read_b128.
__global__ __launch_bounds__(256) void fused1_kernel(
        const unsigned short* __restrict__ xb, const int* __restrict__ srclist,
        const int* __restrict__ offs, const int* __restrict__ deg,
        const bf16_t* __restrict__ Bt, const float* __restrict__ bias,
        unsigned short* __restrict__ H, int n) {
    constexpr int LD = 136;  // 128 + 8 pad
    __shared__ unsigned short a1s[64 * LD];
    int t = threadIdx.x, wave = t >> 6, lane = t & 63;
    int node0 = blockIdx.x * 64;

    // ---- phase 1: gather mean into LDS ----
    for (int i = 0; i < 16; ++i) {
        int nl = wave * 16 + i;
        int node = node0 + nl;
        float s0 = 0.f, s1 = 0.f, u0 = 0.f, u1 = 0.f;
        float v0 = 0.f, v1 = 0.f, w0 = 0.f, w1 = 0.f;
        if (node < n) {
            int st = offs[node], d = deg[node], end = st + d;
            int e = st;
            for (; e + 3 < end; e += 4) {
                int x0 = srclist[e], x1 = srclist[e + 1], x2 = srclist[e + 2], x3 = srclist[e + 3];
                unsigned p0 = *(const unsigned*)(xb + (size_t)x0 * 128 + lane * 2);
                unsigned p1 = *(const unsigned*)(xb + (size_t)x1 * 128 + lane * 2);
                unsigned p2 = *(const unsigned*)(xb + (size_t)x2 * 128 + lane * 2);
                unsigned p3 = *(const unsigned*)(xb + (size_t)x3 * 128 + lane * 2);
                s0 += bfu_lo(p0); s1 += bfu_hi(p0);
                u0 += bfu_lo(p1); u1 += bfu_hi(p1);
                v0 += bfu_lo(p2); v1 += bfu_hi(p2);
                w0 += bfu_lo(p3); w1 += bfu_hi(p3);
            }
            for (; e < end; ++e) {
                unsigned p0 = *(const unsigned*)(xb + (size_t)srclist[e] * 128 + lane * 2);
                s0 += bfu_lo(p0); s1 += bfu_hi(p0);
            }
            float inv = 1.f / fmaxf((float)d, 1.f);
            s0 = ((s0 + u0) + (v0 + w0)) * inv;
            s1 = ((s1 + u1) + (v1 + w1)) * inv;
        }
        *(ushort2*)&a1s[nl * LD + lane * 2] = make_ushort2(f2bf(s0), f2bf(s1));
    }
    __syncthreads();

    // ---- phase 2: GEMM ----
    int quad = lane >> 4, l16 = lane & 15;
    int n0 = wave * 64;
    f32x4 acc[4][4];
#pragma unroll
    for (int i = 0; i < 4; ++i)
#pragma unroll
        for (int j = 0; j < 4; ++j) acc[i][j] = (f32x4)(0.f);

    const bf16_t* Bp = Bt + (size_t)(n0 + l16) * 256 + quad * 8;
    const bf16_t* Rp = (const bf16_t*)xb + (size_t)(node0 + l16) * 128 + quad * 8;

#pragma unroll
    for (int k0 = 0; k0 < 128; k0 += 32) {  // A1 = mean (LDS)
        bf16x8 af[4], bfr[4];
#pragma unroll
        for (int mi = 0; mi < 4; ++mi)
            af[mi] = *(const bf16x8*)&a1s[(mi * 16 + l16) * LD + k0 + quad * 8];
#pragma unroll
        for (int ni = 0; ni < 4; ++ni)
            bfr[ni] = *(const bf16x8*)(Bp + (size_t)ni * 16 * 256 + k0);
#pragma unroll
        for (int mi = 0; mi < 4; ++mi)
#pragma unroll
            for (int ni = 0; ni < 4; ++ni)
                acc[mi][ni] = __builtin_amdgcn_mfma_f32_16x16x32_bf16(af[mi], bfr[ni], acc[mi][ni], 0, 0, 0);
    }
#pragma unroll
    for (int k0 = 0; k0 < 128; k0 += 32) {  // A2 = root (global, streaming)
        bf16x8 af[4], bfr[4];
#pragma unroll
        for (int mi = 0; mi < 4; ++mi)
            af[mi] = *(const bf16x8*)(Rp + (size_t)mi * 16 * 128 + k0);
#pragma unroll
        for (int ni = 0; ni < 4; ++ni)
            bfr[ni] = *(const bf16x8*)(Bp + (size_t)ni * 16 * 256 + 128 + k0);
#pragma unroll
        for (int mi = 0; mi < 4; ++mi)
#pragma unroll
            for (int ni = 0; ni < 4; ++ni)
                acc[mi][ni] = __builtin_amdgcn_mfma_f32_16x16x32_bf16(af[mi], bfr[ni], acc[mi][ni], 0, 0, 0);
    }

    float bv[4];
#pragma unroll
    for (int ni = 0; ni < 4; ++ni) bv[ni] = bias[n0 + ni * 16 + l16];
#pragma unroll
    for (int mi = 0; mi < 4; ++mi) {
#pragma unroll
        for (int r = 0; r < 4; ++r) {
            int row = node0 + mi * 16 + quad * 4 + r;
            if (row < n) {
#pragma unroll
                for (int ni = 0; ni < 4; ++ni) {
                    int col = n0 + ni * 16 + l16;
                    H[(size_t)row * 256 + col] = f2bf(fmaxf(acc[mi][ni][r] + bv[ni], 0.f));
                }
            }
        }
    }
}

// ================= fused SAGE layer 2: same structure, 256-wide rows =================
// LDS pad +8: row stride 528 B = 132 dwords = 4 mod 32 -> 2-way (free), 16B-aligned.
__global__ __launch_bounds__(256) void fused2_kernel(
        const unsigned short* __restrict__ h1, const int* __restrict__ srclist,
        const int* __restrict__ offs, const int* __restrict__ deg,
        const bf16_t* __restrict__ Bt, const float* __restrict__ bias,
        unsigned short* __restrict__ H, int n) {
    constexpr int LD = 264;  // 256 + 8 pad
    __shared__ unsigned short a1s[64 * LD];
    int t = threadIdx.x, wave = t >> 6, lane = t & 63;
    int node0 = blockIdx.x * 64;

    // ---- phase 1: gather mean(h1) into LDS ----
    for (int i = 0; i < 16; ++i) {
        int nl = wave * 16 + i;
        int node = node0 + nl;
        float a0 = 0, a1 = 0, a2 = 0, a3 = 0, b0 = 0, b1 = 0, b2 = 0, b3 = 0;
        float c0 = 0, c1 = 0, c2 = 0, c3 = 0, e0 = 0, e1 = 0, e2 = 0, e3 = 0;
        if (node < n) {
            int st = offs[node], d = deg[node], end = st + d;
            int e = st;
            for (; e + 3 < end; e += 4) {
                int x0 = srclist[e], x1 = srclist[e + 1], x2 = srclist[e + 2], x3 = srclist[e + 3];
                uint2 p0 = *(const uint2*)(h1 + (size_t)x0 * 256 + lane * 4);
                uint2 p1 = *(const uint2*)(h1 + (size_t)x1 * 256 + lane * 4);
                uint2 p2 = *(const uint2*)(h1 + (size_t)x2 * 256 + lane * 4);
                uint2 p3 = *(const uint2*)(h1 + (size_t)x3 * 256 + lane * 4);
                a0 += bfu_lo(p0.x); a1 += bfu_hi(p0.x); a2 += bfu_lo(p0.y); a3 += bfu_hi(p0.y);
                b0 += bfu_lo(p1.x); b1 += bfu_hi(p1.x); b2 += bfu_lo(p1.y); b3 += bfu_hi(p1.y);
                c0 += bfu_lo(p2.x); c1 += bfu_hi(p2.x); c2 += bfu_lo(p2.y); c3 += bfu_hi(p2.y);
                e0 += bfu_lo(p3.x); e1 += bfu_hi(p3.x); e2 += bfu_lo(p3.y); e3 += bfu_hi(p3.y);
            }
            for (; e < end; ++e) {
                uint2 p0 = *(const uint2*)(h1 + (size_t)srclist[e] * 256 + lane * 4);
                a0 += bfu_lo(p0.x); a1 += bfu_hi(p0.x); a2 += bfu_lo(p0.y); a3 += bfu_hi(p0.y);
            }
            float inv = 1.f / fmaxf((float)d, 1.f);
            a0 = ((a0 + b0) + (c0 + e0)) * inv;
            a1 = ((a1 + b1) + (c1 + e1)) * inv;
            a2 = ((a2 + b2) + (c2 + e2)) * inv;
            a3 = ((a3 + b3) + (c3 + e3)) * inv;
        }
        *(ushort4*)&a1s[nl * LD + lane * 4] =
            make_ushort4(f2bf(a0), f2bf(a1), f2bf(a2), f2bf(a3));
    }
    __syncthreads();

    // ---- phase 2: GEMM ----
    int quad = lane >> 4, l16 = lane & 15;
    int n0 = wave * 64;
    f32x4 acc[4][4];
#pragma unroll
    for (int i = 0; i < 4; ++i)
#pragma unroll
        for (int j = 0; j < 4; ++j) acc[i][j] = (f32x4)(0.f);

    const bf16_t* Bp = Bt + (size_t)(n0 + l16) * 512 + quad * 8;
    const bf16_t* Rp = (const bf16_t*)h1 + (size_t)(node0 + l16) * 256 + quad * 8;

#pragma unroll
    for (int k0 = 0; k0 < 256; k0 += 32) {  // A1 = mean (LDS)
        bf16x8 af[4], bfr[4];
#pragma unroll
        for (int mi = 0; mi < 4; ++mi)
            af[mi] = *(const bf16x8*)&a1s[(mi * 16 + l16) * LD + k0 + quad * 8];
#pragma unroll
        for (int ni = 0; ni < 4; ++ni)
            bfr[ni] = *(const bf16x8*)(Bp + (size_t)ni * 16 * 512 + k0);
#pragma unroll
        for (int mi = 0; mi < 4; ++mi)
#pragma unroll
            for (int ni = 0; ni < 4; ++ni)
                acc[mi][ni] = __builtin_amdgcn_mfma_f32_16x16x32_bf16(af[mi], bfr[ni], acc[mi][ni], 0, 0, 0);
    }
#pragma unroll
    for (int k0 = 0; k0 < 256; k0 += 32) {  // A2 = root (global)
        bf16x8 af[4], bfr[4];
#pragma unroll
        for (int mi = 0; mi < 4; ++mi)
            af[mi] = *(const bf16x8*)(Rp + (size_t)mi * 16 * 256 + k0);
#pragma unroll
        for (int ni = 0; ni < 4; ++ni)
            bfr[ni] = *(const bf16x8*)(Bp + (size_t)ni * 16 * 512 + 256 + k0);
#pragma unroll
        for (int mi = 0; mi < 4; ++mi)
#pragma unroll
            for (int ni = 0; ni < 4; ++ni)
                acc[mi][ni] = __builtin_amdgcn_mfma_f32_16x16x32_bf16(af[mi], bfr[ni], acc[mi][ni], 0, 0, 0);
    }

    float bv[4];
#pragma unroll
    for (int ni = 0; ni < 4; ++ni) bv[ni] = bias[n0 + ni * 16 + l16];
#pragma unroll
    for (int mi = 0; mi < 4; ++mi) {
#pragma unroll
        for (int r = 0; r < 4; ++r) {
            int row = node0 + mi * 16 + quad * 4 + r;
            if (row < n) {
#pragma unroll
                for (int ni = 0; ni < 4; ++ni) {
                    int col = n0 + ni * 16 + l16;
                    H[(size_t)row * 256 + col] = f2bf(fmaxf(acc[mi][ni][r] + bv[ni], 0.f));
                }
            }
        }
    }
}

// ---------------- segmented mean pool ----------------
__global__ void pool_kernel(const unsigned short* __restrict__ h2, const int* __restrict__ batch,
                            float* __restrict__ g, float* __restrict__ cnt, int n) {
    int col = threadIdx.x;
    int row0 = blockIdx.x * 256;
    float acc = 0.f;
    int cur = -1, seglen = 0;
    for (int r = 0; r < 256; ++r) {
        int row = row0 + r;
        if (row >= n) break;
        int b = batch[row];
        if (b != cur) {
            if (cur >= 0) {
                atomicAdd(&g[cur * 256 + col], acc);
                if (col == 0) atomicAdd(&cnt[cur], (float)seglen);
            }
            acc = 0.f; cur = b; seglen = 0;
        }
        union { unsigned i; float f; } u;
        u.i = ((unsigned)h2[(size_t)row * 256 + col]) << 16;
        acc += u.f;
        seglen++;
    }
    if (cur >= 0) {
        atomicAdd(&g[cur * 256 + col], acc);
        if (col == 0) atomicAdd(&cnt[cur], (float)seglen);
    }
}

// ---------------- classifier ----------------
__global__ void final_kernel(const float* __restrict__ g, const float* __restrict__ cnt,
                             const float* __restrict__ fcW, const float* __restrict__ fcb,
                             float* __restrict__ out) {
    int t = threadIdx.x;
    for (int o = t; o < NGRAPH * NCLS; o += 256) {
        int gi = o >> 4, c = o & 15;
        float inv = 1.f / fmaxf(cnt[gi], 1.f);
        float dot = 0.f;
        for (int k = 0; k < 256; ++k) dot += g[gi * 256 + k] * fcW[k * 16 + c];
        out[o] = dot * inv + fcb[c];
    }
}

extern "C" void kernel_launch(void* const* d_in, const int* in_sizes, int n_in, void* d_out,
                              int out_size, void* d_ws, size_t ws_size, hipStream_t stream) {
    const float* x   = (const float*)d_in[0];
    const int* edge  = (const int*)d_in[1];
    const int* batch = (const int*)d_in[2];
    const float* W1l = (const float*)d_in[3];
    const float* b1  = (const float*)d_in[4];
    const float* W1r = (const float*)d_in[5];
    const float* W2l = (const float*)d_in[6];
    const float* b2  = (const float*)d_in[7];
    const float* W2r = (const float*)d_in[8];
    const float* fcW = (const float*)d_in[9];
    const float* fcb = (const float*)d_in[10];
    float* out = (float*)d_out;

    const int n = in_sizes[0] / INDIM;   // 100000
    const int E = in_sizes[1] / 2;       // 1600000
    const int* src = edge;
    const int* dst = edge + E;
    const int nbuck = (n + 255) >> 8;    // 391

    char* ws = (char*)d_ws;
    size_t off = 0;
    auto alloc = [&](size_t bytes) {
        size_t p = off;
        off = (off + bytes + 511) & ~(size_t)511;
        return p;
    };
    size_t offs_o    = alloc((size_t)n * 4);
    size_t deg_o     = alloc((size_t)n * 4);         // zeroed
    size_t cnt_o     = alloc(64 * 4);                // zeroed
    size_t g_o       = alloc(64 * 256 * 4);          // zeroed
    size_t zero_end  = off;
    size_t bsum_o    = alloc(1024 * 4);
    size_t gcur_o    = alloc(512 * 4);
    size_t srclist_o = alloc((size_t)E * 4);
    size_t tmp_o     = alloc((size_t)E * 4);
    size_t bt1_o     = alloc(256 * 256 * 2);
    size_t bt2_o     = alloc(256 * 512 * 2);
    size_t xb_o      = alloc((size_t)n * 128 * 2);
    size_t h1_o      = alloc((size_t)n * 256 * 2);
    size_t h2_o      = alloc((size_t)n * 256 * 2);

    int*   offs    = (int*)(ws + offs_o);
    int*   deg     = (int*)(ws + deg_o);
    float* cnt     = (float*)(ws + cnt_o);
    float* g       = (float*)(ws + g_o);
    int*   bsum    = (int*)(ws + bsum_o);
    int*   gcur    = (int*)(ws + gcur_o);
    int*   srclist = (int*)(ws + srclist_o);
    unsigned*       tmp  = (unsigned*)(ws + tmp_o);
    unsigned short* Bt1  = (unsigned short*)(ws + bt1_o);
    unsigned short* Bt2  = (unsigned short*)(ws + bt2_o);
    unsigned short* xb16 = (unsigned short*)(ws + xb_o);
    unsigned short* h1b  = (unsigned short*)(ws + h1_o);
    unsigned short* h2b  = (unsigned short*)(ws + h2_o);

    hipMemsetAsync(ws + deg_o, 0, zero_end - deg_o, stream);

    int eb = (E + 255) / 256;
    int nb = (n + 255) / 256;  // 391
    hist_kernel<<<eb, 256, 0, stream>>>(dst, deg, E);
    scan1_kernel<<<nb, 256, 0, stream>>>(deg, bsum, n);
    scan2_kernel<<<1, 1024, 0, stream>>>(bsum, nb);
    scan3_kernel<<<nb, 256, 0, stream>>>(deg, bsum, offs, n);
    initcur_kernel<<<(nbuck + 255) / 256, 256, 0, stream>>>(offs, gcur, nbuck);
    binA_kernel<<<(E + CHUNK - 1) / CHUNK, 256, 0, stream>>>(src, dst, gcur, tmp, E, nbuck);
    binB_kernel<<<nbuck, 256, 0, stream>>>(tmp, offs, srclist, E, n);

    cast_x_kernel<<<(n * INDIM / 4 + 255) / 256, 256, 0, stream>>>(x, xb16, n * INDIM / 4);
    wcast1_kernel<<<256, 256, 0, stream>>>(W1l, W1r, Bt1);
    wcast2_kernel<<<512, 256, 0, stream>>>(W2l, W2r, Bt2);

    int gemmb = (n + 63) / 64;  // 1563
    fused1_kernel<<<gemmb, 256, 0, stream>>>(xb16, srclist, offs, deg,
                                             (const bf16_t*)Bt1, b1, h1b, n);
    fused2_kernel<<<gemmb, 256, 0, stream>>>(h1b, srclist, offs, deg,
                                             (const bf16_t*)Bt2, b2, h2b, n);

    pool_kernel<<<nb, 256, 0, stream>>>(h2b, batch, g, cnt, n);
    final_kernel<<<1, 256, 0, stream>>>(g, cnt, fcW, fcb, out);
}

// Round 6
// 662.539 us; speedup vs baseline: 1.3804x; 1.3804x over previous
//
#include <hip/hip_runtime.h>

#define INDIM 128
#define HID 256
#define NCLS 16
#define NGRAPH 64
#define CHUNK 8192

typedef __bf16 bf16_t;
typedef bf16_t bf16x8 __attribute__((ext_vector_type(8)));
typedef float f32x4 __attribute__((ext_vector_type(4)));

__device__ __forceinline__ float bfu_lo(unsigned v) {
    union { unsigned i; float f; } u; u.i = v << 16; return u.f;
}
__device__ __forceinline__ float bfu_hi(unsigned v) {
    union { unsigned i; float f; } u; u.i = v & 0xffff0000u; return u.f;
}
__device__ __forceinline__ unsigned short f2bf(float f) {  // RNE
    union { float f; unsigned i; } u; u.f = f;
    unsigned b = u.i;
    return (unsigned short)((b + 0x7fffu + ((b >> 16) & 1u)) >> 16);
}

// async 16B global->LDS (fire-and-forget; lds dest = wave-uniform base + lane*16)
typedef __attribute__((address_space(1))) const unsigned gu32_t;
typedef __attribute__((address_space(3))) unsigned lu32_t;
__device__ __forceinline__ void gl_lds16(const void* g, void* l) {
    __builtin_amdgcn_global_load_lds((gu32_t*)g, (lu32_t*)l, 16, 0, 0);
}

// ---------------- CSR build ----------------
__global__ void hist_kernel(const int* __restrict__ dst, int* __restrict__ deg, int E) {
    int e = blockIdx.x * blockDim.x + threadIdx.x;
    if (e < E) atomicAdd(&deg[dst[e]], 1);
}

__global__ void scan1_kernel(const int* __restrict__ deg, int* __restrict__ bsum, int n) {
    __shared__ int s[256];
    int t = threadIdx.x;
    int i = blockIdx.x * 256 + t;
    s[t] = (i < n) ? deg[i] : 0;
    __syncthreads();
    for (int off = 128; off > 0; off >>= 1) {
        if (t < off) s[t] += s[t + off];
        __syncthreads();
    }
    if (t == 0) bsum[blockIdx.x] = s[0];
}

__global__ void scan2_kernel(int* bsum, int nb) {
    __shared__ int s[1024];
    int t = threadIdx.x;
    int v = (t < nb) ? bsum[t] : 0;
    s[t] = v;
    __syncthreads();
    for (int off = 1; off < 1024; off <<= 1) {
        int u = (t >= off) ? s[t - off] : 0;
        __syncthreads();
        s[t] += u;
        __syncthreads();
    }
    if (t < nb) bsum[t] = s[t] - v;  // exclusive
}

__global__ void scan3_kernel(const int* __restrict__ deg, const int* __restrict__ bsum,
                             int* __restrict__ offs, int n) {
    __shared__ int s[256];
    int t = threadIdx.x;
    int i = blockIdx.x * 256 + t;
    int v = (i < n) ? deg[i] : 0;
    s[t] = v;
    __syncthreads();
    for (int off = 1; off < 256; off <<= 1) {
        int u = (t >= off) ? s[t - off] : 0;
        __syncthreads();
        s[t] += u;
        __syncthreads();
    }
    if (i < n) offs[i] = s[t] - v + bsum[blockIdx.x];
}

// ---------------- two-phase locality-aware edge sort ----------------
__global__ void initcur_kernel(const int* __restrict__ offs, int* __restrict__ gcur, int nbuck) {
    int t = blockIdx.x * blockDim.x + threadIdx.x;
    if (t < nbuck) gcur[t] = offs[t << 8];
}

__global__ __launch_bounds__(256) void binA_kernel(const int* __restrict__ src,
                                                   const int* __restrict__ dst,
                                                   int* __restrict__ gcur,
                                                   unsigned* __restrict__ tmp,
                                                   int E, int nbuck) {
    __shared__ int hist[512];
    __shared__ int base[512];
    int t = threadIdx.x;
    int e0 = blockIdx.x * CHUNK;
    int e1 = min(e0 + CHUNK, E);
    for (int i = t; i < nbuck; i += 256) hist[i] = 0;
    __syncthreads();
    for (int e = e0 + t; e < e1; e += 256) atomicAdd(&hist[dst[e] >> 8], 1);
    __syncthreads();
    for (int i = t; i < nbuck; i += 256) {
        int c = hist[i];
        base[i] = (c > 0) ? atomicAdd(&gcur[i], c) : 0;
    }
    __syncthreads();
    for (int e = e0 + t; e < e1; e += 256) {
        int d = dst[e];
        int p = atomicAdd(&base[d >> 8], 1);
        tmp[p] = ((unsigned)(d & 255) << 17) | (unsigned)src[e];  // src < 2^17
    }
}

__global__ __launch_bounds__(256) void binB_kernel(const unsigned* __restrict__ tmp,
                                                   const int* __restrict__ offs,
                                                   int* __restrict__ srclist, int E, int n) {
    __shared__ int cur[256];
    int b = blockIdx.x;
    int node0 = b << 8;
    int nnodes = min(256, n - node0);
    int t = threadIdx.x;
    if (t < nnodes) cur[t] = offs[node0 + t];
    __syncthreads();
    int ebeg = offs[node0];
    int eend = (node0 + 256 < n) ? offs[node0 + 256] : E;
    for (int e = ebeg + t; e < eend; e += 256) {
        unsigned v = tmp[e];
        int p = atomicAdd(&cur[v >> 17], 1);
        srclist[p] = (int)(v & 0x1FFFFu);
    }
}

// ---------------- casts ----------------
__global__ void cast_x_kernel(const float* __restrict__ x, unsigned short* __restrict__ xb,
                              int total4) {
    int idx = blockIdx.x * blockDim.x + threadIdx.x;
    if (idx >= total4) return;
    int i4 = idx * 4;
    float4 v = *(const float4*)(x + i4);
    *(ushort4*)(xb + i4) = make_ushort4(f2bf(v.x), f2bf(v.y), f2bf(v.z), f2bf(v.w));
}

// Bt1[n*256 + k] = bf16( k<128 ? W1l[k][n] : W1r[k-128][n] )
__global__ void wcast1_kernel(const float* __restrict__ Wl, const float* __restrict__ Wr,
                              unsigned short* __restrict__ Bt) {
    int idx = blockIdx.x * blockDim.x + threadIdx.x;  // 65536
    int n = idx >> 8, k = idx & 255;
    float v = (k < 128) ? Wl[(size_t)k * 256 + n] : Wr[(size_t)(k - 128) * 256 + n];
    Bt[(size_t)n * 256 + k] = f2bf(v);
}

// Bt2[n*512 + k] = bf16( k<256 ? W2l[k][n] : W2r[k-256][n] )
__global__ void wcast2_kernel(const float* __restrict__ Wl, const float* __restrict__ Wr,
                              unsigned short* __restrict__ Bt) {
    int idx = blockIdx.x * blockDim.x + threadIdx.x;  // 131072
    int n = idx >> 9, k = idx & 511;
    float v = (k < 256) ? Wl[(size_t)k * 256 + n] : Wr[(size_t)(k - 256) * 256 + n];
    Bt[(size_t)n * 512 + k] = f2bf(v);
}

// ---------------- mean aggregation (R4-proven: one wave per node, 4 chains) ----------------
__global__ void agg1_kernel(const unsigned short* __restrict__ xb, const int* __restrict__ srclist,
                            const int* __restrict__ offs, const int* __restrict__ deg,
                            unsigned short* __restrict__ mean, int n) {
    int gid = blockIdx.x * blockDim.x + threadIdx.x;
    int node = gid >> 6, lane = gid & 63;
    if (node >= n) return;
    int st = offs[node], d = deg[node], end = st + d;
    float a0 = 0.f, a1 = 0.f, b0 = 0.f, b1 = 0.f;
    float c0 = 0.f, c1 = 0.f, d0 = 0.f, d1 = 0.f;
    int e = st;
    for (; e + 3 < end; e += 4) {
        int s0 = srclist[e], s1 = srclist[e + 1], s2 = srclist[e + 2], s3 = srclist[e + 3];
        unsigned v0 = *(const unsigned*)(xb + (size_t)s0 * 128 + lane * 2);
        unsigned v1 = *(const unsigned*)(xb + (size_t)s1 * 128 + lane * 2);
        unsigned v2 = *(const unsigned*)(xb + (size_t)s2 * 128 + lane * 2);
        unsigned v3 = *(const unsigned*)(xb + (size_t)s3 * 128 + lane * 2);
        a0 += bfu_lo(v0); a1 += bfu_hi(v0);
        b0 += bfu_lo(v1); b1 += bfu_hi(v1);
        c0 += bfu_lo(v2); c1 += bfu_hi(v2);
        d0 += bfu_lo(v3); d1 += bfu_hi(v3);
    }
    for (; e < end; ++e) {
        unsigned v0 = *(const unsigned*)(xb + (size_t)srclist[e] * 128 + lane * 2);
        a0 += bfu_lo(v0); a1 += bfu_hi(v0);
    }
    float inv = 1.f / fmaxf((float)d, 1.f);
    ushort2 o = make_ushort2(f2bf(((a0 + b0) + (c0 + d0)) * inv),
                             f2bf(((a1 + b1) + (c1 + d1)) * inv));
    *(ushort2*)(mean + (size_t)node * 128 + lane * 2) = o;
}

__global__ void agg2_kernel(const unsigned short* __restrict__ h1, const int* __restrict__ srclist,
                            const int* __restrict__ offs, const int* __restrict__ deg,
                            unsigned short* __restrict__ mean, int n) {
    int gid = blockIdx.x * blockDim.x + threadIdx.x;
    int node = gid >> 6, lane = gid & 63;
    if (node >= n) return;
    int st = offs[node], d = deg[node], end = st + d;
    float a0 = 0, a1 = 0, a2 = 0, a3 = 0, b0 = 0, b1 = 0, b2 = 0, b3 = 0;
    float c0 = 0, c1 = 0, c2 = 0, c3 = 0, e0 = 0, e1 = 0, e2 = 0, e3 = 0;
    int e = st;
    for (; e + 3 < end; e += 4) {
        int s0 = srclist[e], s1 = srclist[e + 1], s2 = srclist[e + 2], s3 = srclist[e + 3];
        uint2 v0 = *(const uint2*)(h1 + (size_t)s0 * 256 + lane * 4);
        uint2 v1 = *(const uint2*)(h1 + (size_t)s1 * 256 + lane * 4);
        uint2 v2 = *(const uint2*)(h1 + (size_t)s2 * 256 + lane * 4);
        uint2 v3 = *(const uint2*)(h1 + (size_t)s3 * 256 + lane * 4);
        a0 += bfu_lo(v0.x); a1 += bfu_hi(v0.x); a2 += bfu_lo(v0.y); a3 += bfu_hi(v0.y);
        b0 += bfu_lo(v1.x); b1 += bfu_hi(v1.x); b2 += bfu_lo(v1.y); b3 += bfu_hi(v1.y);
        c0 += bfu_lo(v2.x); c1 += bfu_hi(v2.x); c2 += bfu_lo(v2.y); c3 += bfu_hi(v2.y);
        e0 += bfu_lo(v3.x); e1 += bfu_hi(v3.x); e2 += bfu_lo(v3.y); e3 += bfu_hi(v3.y);
    }
    for (; e < end; ++e) {
        uint2 v0 = *(const uint2*)(h1 + (size_t)srclist[e] * 256 + lane * 4);
        a0 += bfu_lo(v0.x); a1 += bfu_hi(v0.x); a2 += bfu_lo(v0.y); a3 += bfu_hi(v0.y);
    }
    float inv = 1.f / fmaxf((float)d, 1.f);
    ushort4 o = make_ushort4(f2bf(((a0 + b0) + (c0 + e0)) * inv),
                             f2bf(((a1 + b1) + (c1 + e1)) * inv),
                             f2bf(((a2 + b2) + (c2 + e2)) * inv),
                             f2bf(((a3 + b3) + (c3 + e3)) * inv));
    *(ushort4*)(mean + (size_t)node * 256 + lane * 4) = o;
}

// ======== MFMA GEMM with async A-staging: H = relu([A1|A2] @ Bt^T + bias) ========
// Block: 256 thr / 4 waves; tile 64 rows x 256 cols; K-chunks of 64 (BK).
// A chunk (64x64 bf16 = 8 KB) staged via global_load_lds (16B/lane), single-buffered
// m97-style (stage -> barrier -> compute -> barrier). XOR-swizzle on k-blocks:
// LDS[r][kb] holds global k-block (kb ^ (r&7)) -> ds_read_b128 A-frags are <=2-way
// bank-aliased (free per m136). B-frags load direct from global (<=512 KB, L2-hot).
// Outstanding staging bytes per CU (~4 blocks x 8 KB) >> 9 KB Little's-law need.
template <int KH>  // per-half K: 128 (layer1) or 256 (layer2)
__global__ __launch_bounds__(256) void gemm_kernel(
        const bf16_t* __restrict__ A1, const bf16_t* __restrict__ A2,
        const bf16_t* __restrict__ Bt, const float* __restrict__ bias,
        unsigned short* __restrict__ H, int M) {
    constexpr int KT = 2 * KH;
    constexpr int NC = KT / 64;    // chunks
    constexpr int CPH = KH / 64;   // chunks per half
    __shared__ unsigned short As[64 * 64];  // 8 KB
    int t = threadIdx.x, wave = t >> 6, lane = t & 63;
    int quad = lane >> 4, l16 = lane & 15;
    int row0 = blockIdx.x * 64, n0 = wave * 64;

    f32x4 acc[4][4];
#pragma unroll
    for (int i = 0; i < 4; ++i)
#pragma unroll
        for (int j = 0; j < 4; ++j) acc[i][j] = (f32x4)(0.f);

    // staging geometry: 2 issues/chunk; issue j covers LDS rows j*32 + wave*8 .. +8
    int rA = wave * 8 + (lane >> 3);       // LDS row, issue 0
    int kb = lane & 7;                     // LDS k-block slot
    int kswA = (kb ^ (rA & 7)) << 3;       // swizzled global k-offset (elements)
    unsigned short* ldsA = &As[(size_t)(wave * 8) * 64];        // wave-uniform
    unsigned short* ldsB = &As[(size_t)(32 + wave * 8) * 64];   // wave-uniform

    const bf16_t* Bp = Bt + (size_t)(n0 + l16) * KT + quad * 8;

    for (int c = 0; c < NC; ++c) {
        const bf16_t* Ah = (c < CPH) ? A1 : A2;
        int kk = ((c < CPH) ? c : (c - CPH)) * 64;
        // stage 64x64 chunk (rows may run past M: lands in adjacent ws region, masked later)
        gl_lds16(Ah + (size_t)(row0 + rA) * KH + kk + kswA, ldsA);
        gl_lds16(Ah + (size_t)(row0 + 32 + rA) * KH + kk + kswA, ldsB);
        __syncthreads();  // drains vmcnt -> staged data visible
        int bk = c * 64;  // global k base in concatenated B
#pragma unroll
        for (int sub = 0; sub < 2; ++sub) {
            bf16x8 af[4], bfr[4];
#pragma unroll
            for (int mi = 0; mi < 4; ++mi) {
                int r = mi * 16 + l16;
                int qb = sub * 4 + quad;
                af[mi] = *(const bf16x8*)&As[r * 64 + ((qb ^ (r & 7)) << 3)];
            }
#pragma unroll
            for (int ni = 0; ni < 4; ++ni)
                bfr[ni] = *(const bf16x8*)(Bp + (size_t)(ni * 16) * KT + bk + sub * 32);
#pragma unroll
            for (int mi = 0; mi < 4; ++mi)
#pragma unroll
                for (int ni = 0; ni < 4; ++ni)
                    acc[mi][ni] = __builtin_amdgcn_mfma_f32_16x16x32_bf16(
                        af[mi], bfr[ni], acc[mi][ni], 0, 0, 0);
        }
        __syncthreads();  // compute done before next chunk overwrites As
    }

    float bv[4];
#pragma unroll
    for (int ni = 0; ni < 4; ++ni) bv[ni] = bias[n0 + ni * 16 + l16];
#pragma unroll
    for (int mi = 0; mi < 4; ++mi) {
#pragma unroll
        for (int r = 0; r < 4; ++r) {
            int row = row0 + mi * 16 + quad * 4 + r;
            if (row < M) {
#pragma unroll
                for (int ni = 0; ni < 4; ++ni) {
                    int col = n0 + ni * 16 + l16;
                    H[(size_t)row * 256 + col] = f2bf(fmaxf(acc[mi][ni][r] + bv[ni], 0.f));
                }
            }
        }
    }
}

// ---------------- segmented mean pool ----------------
__global__ void pool_kernel(const unsigned short* __restrict__ h2, const int* __restrict__ batch,
                            float* __restrict__ g, float* __restrict__ cnt, int n) {
    int col = threadIdx.x;
    int row0 = blockIdx.x * 256;
    float acc = 0.f;
    int cur = -1, seglen = 0;
    for (int r = 0; r < 256; ++r) {
        int row = row0 + r;
        if (row >= n) break;
        int b = batch[row];
        if (b != cur) {
            if (cur >= 0) {
                atomicAdd(&g[cur * 256 + col], acc);
                if (col == 0) atomicAdd(&cnt[cur], (float)seglen);
            }
            acc = 0.f; cur = b; seglen = 0;
        }
        union { unsigned i; float f; } u;
        u.i = ((unsigned)h2[(size_t)row * 256 + col]) << 16;
        acc += u.f;
        seglen++;
    }
    if (cur >= 0) {
        atomicAdd(&g[cur * 256 + col], acc);
        if (col == 0) atomicAdd(&cnt[cur], (float)seglen);
    }
}

// ---------------- classifier ----------------
__global__ void final_kernel(const float* __restrict__ g, const float* __restrict__ cnt,
                             const float* __restrict__ fcW, const float* __restrict__ fcb,
                             float* __restrict__ out) {
    int t = threadIdx.x;
    for (int o = t; o < NGRAPH * NCLS; o += 256) {
        int gi = o >> 4, c = o & 15;
        float inv = 1.f / fmaxf(cnt[gi], 1.f);
        float dot = 0.f;
        for (int k = 0; k < 256; ++k) dot += g[gi * 256 + k] * fcW[k * 16 + c];
        out[o] = dot * inv + fcb[c];
    }
}

extern "C" void kernel_launch(void* const* d_in, const int* in_sizes, int n_in, void* d_out,
                              int out_size, void* d_ws, size_t ws_size, hipStream_t stream) {
    const float* x   = (const float*)d_in[0];
    const int* edge  = (const int*)d_in[1];
    const int* batch = (const int*)d_in[2];
    const float* W1l = (const float*)d_in[3];
    const float* b1  = (const float*)d_in[4];
    const float* W1r = (const float*)d_in[5];
    const float* W2l = (const float*)d_in[6];
    const float* b2  = (const float*)d_in[7];
    const float* W2r = (const float*)d_in[8];
    const float* fcW = (const float*)d_in[9];
    const float* fcb = (const float*)d_in[10];
    float* out = (float*)d_out;

    const int n = in_sizes[0] / INDIM;   // 100000
    const int E = in_sizes[1] / 2;       // 1600000
    const int* src = edge;
    const int* dst = edge + E;
    const int nbuck = (n + 255) >> 8;    // 391

    char* ws = (char*)d_ws;
    size_t off = 0;
    auto alloc = [&](size_t bytes) {
        size_t p = off;
        off = (off + bytes + 511) & ~(size_t)511;
        return p;
    };
    size_t offs_o    = alloc((size_t)n * 4);
    size_t deg_o     = alloc((size_t)n * 4);          // zeroed
    size_t cnt_o     = alloc(64 * 4);                 // zeroed
    size_t g_o       = alloc(64 * 256 * 4);           // zeroed
    size_t zero_end  = off;
    size_t bsum_o    = alloc(1024 * 4);
    size_t gcur_o    = alloc(512 * 4);
    size_t srclist_o = alloc((size_t)E * 4);
    size_t bt1_o     = alloc(256 * 256 * 2);
    size_t bt2_o     = alloc(256 * 512 * 2);
    size_t xbm2_o    = alloc((size_t)n * 256 * 2);    // xb16 (n*128*2) -> mean2 (n*256*2)
    size_t mean1_o   = alloc((size_t)n * 128 * 2);
    size_t h1_o      = alloc((size_t)n * 256 * 2);
    size_t h2_o      = alloc((size_t)n * 256 * 2);    // tmp (CSR build) aliases here

    int*   offs    = (int*)(ws + offs_o);
    int*   deg     = (int*)(ws + deg_o);
    float* cnt     = (float*)(ws + cnt_o);
    float* g       = (float*)(ws + g_o);
    int*   bsum    = (int*)(ws + bsum_o);
    int*   gcur    = (int*)(ws + gcur_o);
    int*   srclist = (int*)(ws + srclist_o);
    unsigned short* Bt1   = (unsigned short*)(ws + bt1_o);
    unsigned short* Bt2   = (unsigned short*)(ws + bt2_o);
    unsigned short* xb16  = (unsigned short*)(ws + xbm2_o);  // dead after gemm1
    unsigned short* mean2 = (unsigned short*)(ws + xbm2_o);  // written by agg2 (after gemm1)
    unsigned short* mean1 = (unsigned short*)(ws + mean1_o);
    unsigned short* h1b   = (unsigned short*)(ws + h1_o);
    unsigned*       tmp   = (unsigned*)(ws + h2_o);          // dead before gemm2 writes h2
    unsigned short* h2b   = (unsigned short*)(ws + h2_o);

    hipMemsetAsync(ws + deg_o, 0, zero_end - deg_o, stream);

    int eb = (E + 255) / 256;
    int nb = (n + 255) / 256;  // 391
    hist_kernel<<<eb, 256, 0, stream>>>(dst, deg, E);
    scan1_kernel<<<nb, 256, 0, stream>>>(deg, bsum, n);
    scan2_kernel<<<1, 1024, 0, stream>>>(bsum, nb);
    scan3_kernel<<<nb, 256, 0, stream>>>(deg, bsum, offs, n);
    initcur_kernel<<<(nbuck + 255) / 256, 256, 0, stream>>>(offs, gcur, nbuck);
    binA_kernel<<<(E + CHUNK - 1) / CHUNK, 256, 0, stream>>>(src, dst, gcur, tmp, E, nbuck);
    binB_kernel<<<nbuck, 256, 0, stream>>>(tmp, offs, srclist, E, n);

    cast_x_kernel<<<(n * INDIM / 4 + 255) / 256, 256, 0, stream>>>(x, xb16, n * INDIM / 4);
    wcast1_kernel<<<256, 256, 0, stream>>>(W1l, W1r, Bt1);
    wcast2_kernel<<<512, 256, 0, stream>>>(W2l, W2r, Bt2);

    int aggb = (n * 64 + 255) / 256;
    int gemmb = (n + 63) / 64;  // 1563

    agg1_kernel<<<aggb, 256, 0, stream>>>(xb16, srclist, offs, deg, mean1, n);
    gemm_kernel<128><<<gemmb, 256, 0, stream>>>(
        (const bf16_t*)mean1, (const bf16_t*)xb16, (const bf16_t*)Bt1, b1, h1b, n);
    agg2_kernel<<<aggb, 256, 0, stream>>>(h1b, srclist, offs, deg, mean2, n);
    gemm_kernel<256><<<gemmb, 256, 0, stream>>>(
        (const bf16_t*)mean2, (const bf16_t*)h1b, (const bf16_t*)Bt2, b2, h2b, n);

    pool_kernel<<<nb, 256, 0, stream>>>(h2b, batch, g, cnt, n);
    final_kernel<<<1, 256, 0, stream>>>(g, cnt, fcW, fcb, out);
}

// Round 7
// 641.525 us; speedup vs baseline: 1.4257x; 1.0328x over previous
//
#include <hip/hip_runtime.h>

#define INDIM 128
#define HID 256
#define NCLS 16
#define NGRAPH 64
#define CHUNK 8192

typedef __bf16 bf16_t;
typedef bf16_t bf16x8 __attribute__((ext_vector_type(8)));
typedef float f32x4 __attribute__((ext_vector_type(4)));

__device__ __forceinline__ float bfu_lo(unsigned v) {
    union { unsigned i; float f; } u; u.i = v << 16; return u.f;
}
__device__ __forceinline__ float bfu_hi(unsigned v) {
    union { unsigned i; float f; } u; u.i = v & 0xffff0000u; return u.f;
}
__device__ __forceinline__ unsigned short f2bf(float f) {  // RNE
    union { float f; unsigned i; } u; u.f = f;
    unsigned b = u.i;
    return (unsigned short)((b + 0x7fffu + ((b >> 16) & 1u)) >> 16);
}
__device__ __forceinline__ unsigned packbf(float lo, float hi) {
    return (unsigned)f2bf(lo) | ((unsigned)f2bf(hi) << 16);
}

// async 16B global->LDS
typedef __attribute__((address_space(1))) const unsigned gu32_t;
typedef __attribute__((address_space(3))) unsigned lu32_t;
__device__ __forceinline__ void gl_lds16(const void* g, void* l) {
    __builtin_amdgcn_global_load_lds((gu32_t*)g, (lu32_t*)l, 16, 0, 0);
}

#define ACC8(a, v)                                   \
    do {                                             \
        a[0] += bfu_lo((v).x); a[1] += bfu_hi((v).x); \
        a[2] += bfu_lo((v).y); a[3] += bfu_hi((v).y); \
        a[4] += bfu_lo((v).z); a[5] += bfu_hi((v).z); \
        a[6] += bfu_lo((v).w); a[7] += bfu_hi((v).w); \
    } while (0)

// ---------------- CSR build ----------------
__global__ void hist_kernel(const int* __restrict__ dst, int* __restrict__ deg, int E) {
    int e = blockIdx.x * blockDim.x + threadIdx.x;
    if (e < E) atomicAdd(&deg[dst[e]], 1);
}

__global__ void scan1_kernel(const int* __restrict__ deg, int* __restrict__ bsum, int n) {
    __shared__ int s[256];
    int t = threadIdx.x;
    int i = blockIdx.x * 256 + t;
    s[t] = (i < n) ? deg[i] : 0;
    __syncthreads();
    for (int off = 128; off > 0; off >>= 1) {
        if (t < off) s[t] += s[t + off];
        __syncthreads();
    }
    if (t == 0) bsum[blockIdx.x] = s[0];
}

__global__ void scan2_kernel(int* bsum, int nb) {
    __shared__ int s[1024];
    int t = threadIdx.x;
    int v = (t < nb) ? bsum[t] : 0;
    s[t] = v;
    __syncthreads();
    for (int off = 1; off < 1024; off <<= 1) {
        int u = (t >= off) ? s[t - off] : 0;
        __syncthreads();
        s[t] += u;
        __syncthreads();
    }
    if (t < nb) bsum[t] = s[t] - v;  // exclusive
}

// also seeds gcur (was a separate initcur launch): gcur[b] = offs[b*256] = bsum[b]
__global__ void scan3_kernel(const int* __restrict__ deg, const int* __restrict__ bsum,
                             int* __restrict__ offs, int* __restrict__ gcur, int n) {
    __shared__ int s[256];
    int t = threadIdx.x;
    int i = blockIdx.x * 256 + t;
    int v = (i < n) ? deg[i] : 0;
    s[t] = v;
    __syncthreads();
    for (int off = 1; off < 256; off <<= 1) {
        int u = (t >= off) ? s[t - off] : 0;
        __syncthreads();
        s[t] += u;
        __syncthreads();
    }
    if (i < n) offs[i] = s[t] - v + bsum[blockIdx.x];
    if (t == 0) gcur[blockIdx.x] = bsum[blockIdx.x];
}

// ---------------- two-phase locality-aware edge sort ----------------
__global__ __launch_bounds__(256) void binA_kernel(const int* __restrict__ src,
                                                   const int* __restrict__ dst,
                                                   int* __restrict__ gcur,
                                                   unsigned* __restrict__ tmp,
                                                   int E, int nbuck) {
    __shared__ int hist[512];
    __shared__ int base[512];
    int t = threadIdx.x;
    int e0 = blockIdx.x * CHUNK;
    int e1 = min(e0 + CHUNK, E);
    for (int i = t; i < nbuck; i += 256) hist[i] = 0;
    __syncthreads();
    for (int e = e0 + t; e < e1; e += 256) atomicAdd(&hist[dst[e] >> 8], 1);
    __syncthreads();
    for (int i = t; i < nbuck; i += 256) {
        int c = hist[i];
        base[i] = (c > 0) ? atomicAdd(&gcur[i], c) : 0;
    }
    __syncthreads();
    for (int e = e0 + t; e < e1; e += 256) {
        int d = dst[e];
        int p = atomicAdd(&base[d >> 8], 1);
        tmp[p] = ((unsigned)(d & 255) << 17) | (unsigned)src[e];  // src < 2^17
    }
}

__global__ __launch_bounds__(256) void binB_kernel(const unsigned* __restrict__ tmp,
                                                   const int* __restrict__ offs,
                                                   int* __restrict__ srclist, int E, int n) {
    __shared__ int cur[256];
    int b = blockIdx.x;
    int node0 = b << 8;
    int nnodes = min(256, n - node0);
    int t = threadIdx.x;
    if (t < nnodes) cur[t] = offs[node0 + t];
    __syncthreads();
    int ebeg = offs[node0];
    int eend = (node0 + 256 < n) ? offs[node0 + 256] : E;
    for (int e = ebeg + t; e < eend; e += 256) {
        unsigned v = tmp[e];
        int p = atomicAdd(&cur[v >> 17], 1);
        srclist[p] = (int)(v & 0x1FFFFu);
    }
}

// ---------------- merged prep: cast x -> bf16, build Bt1/Bt2 (was 3 launches) ----------------
__global__ void prep_kernel(const float* __restrict__ x, unsigned short* __restrict__ xb,
                            const float* __restrict__ W1l, const float* __restrict__ W1r,
                            unsigned short* __restrict__ Bt1,
                            const float* __restrict__ W2l, const float* __restrict__ W2r,
                            unsigned short* __restrict__ Bt2, int castb) {
    int b = blockIdx.x, t = threadIdx.x;
    if (b < castb) {
        int i4 = (b * 256 + t) * 4;
        float4 v = *(const float4*)(x + i4);
        *(ushort4*)(xb + i4) = make_ushort4(f2bf(v.x), f2bf(v.y), f2bf(v.z), f2bf(v.w));
    } else if (b < castb + 256) {
        int idx = (b - castb) * 256 + t;
        int nn = idx >> 8, k = idx & 255;
        float v = (k < 128) ? W1l[(size_t)k * 256 + nn] : W1r[(size_t)(k - 128) * 256 + nn];
        Bt1[(size_t)nn * 256 + k] = f2bf(v);
    } else {
        int idx = (b - castb - 256) * 256 + t;
        int nn = idx >> 9, k = idx & 511;
        float v = (k < 256) ? W2l[(size_t)k * 256 + nn] : W2r[(size_t)(k - 256) * 256 + nn];
        Bt2[(size_t)nn * 512 + k] = f2bf(v);
    }
}

// ---------------- mean aggregation, wide-gather ----------------
// agg1: quarter-wave per row (16 lanes x 16B = 256B row); one load instr = 4 edges.
__global__ void agg1_kernel(const unsigned short* __restrict__ xb, const int* __restrict__ srclist,
                            const int* __restrict__ offs, const int* __restrict__ deg,
                            unsigned short* __restrict__ mean, int n) {
    int gid = blockIdx.x * blockDim.x + threadIdx.x;
    int node = gid >> 6, lane = gid & 63;
    if (node >= n) return;
    int q = lane >> 4, sub = lane & 15;
    int st = __builtin_amdgcn_readfirstlane(offs[node]);
    int d = __builtin_amdgcn_readfirstlane(deg[node]);
    int end = st + d;
    float aA[8] = {0, 0, 0, 0, 0, 0, 0, 0}, aB[8] = {0, 0, 0, 0, 0, 0, 0, 0};
    const unsigned short* rb = xb + sub * 8;
    int e = st;
    for (; e + 7 < end; e += 8) {  // 2 loads -> 8 edges
        int s0 = srclist[e + q];
        int s1 = srclist[e + 4 + q];
        uint4 v0 = *(const uint4*)(rb + (size_t)s0 * 128);
        uint4 v1 = *(const uint4*)(rb + (size_t)s1 * 128);
        ACC8(aA, v0);
        ACC8(aB, v1);
    }
    for (; e + 3 < end; e += 4) {
        int s0 = srclist[e + q];
        uint4 v0 = *(const uint4*)(rb + (size_t)s0 * 128);
        ACC8(aA, v0);
    }
    int rem = end - e;
    if (rem > 0) {  // 1..3 edges; lanes with q >= rem contribute 0
        int s0 = srclist[e + ((q < rem) ? q : 0)];
        uint4 v0 = *(const uint4*)(rb + (size_t)s0 * 128);
        if (q < rem) ACC8(aA, v0);
    }
    float inv = 1.f / fmaxf((float)d, 1.f);
    float tot[8];
#pragma unroll
    for (int i = 0; i < 8; ++i) {
        float s = aA[i] + aB[i];
        s += __shfl_xor(s, 16);
        s += __shfl_xor(s, 32);
        tot[i] = s * inv;
    }
    if (lane < 16) {
        uint4 o;
        o.x = packbf(tot[0], tot[1]);
        o.y = packbf(tot[2], tot[3]);
        o.z = packbf(tot[4], tot[5]);
        o.w = packbf(tot[6], tot[7]);
        *(uint4*)(mean + (size_t)node * 128 + sub * 8) = o;
    }
}

// agg2: half-wave per row (32 lanes x 16B = 512B row); one load instr = 2 edges; 8-edge unroll.
__global__ void agg2_kernel(const unsigned short* __restrict__ h1, const int* __restrict__ srclist,
                            const int* __restrict__ offs, const int* __restrict__ deg,
                            unsigned short* __restrict__ mean, int n) {
    int gid = blockIdx.x * blockDim.x + threadIdx.x;
    int node = gid >> 6, lane = gid & 63;
    if (node >= n) return;
    int half = lane >> 5, sub = lane & 31;
    int st = __builtin_amdgcn_readfirstlane(offs[node]);
    int d = __builtin_amdgcn_readfirstlane(deg[node]);
    int end = st + d;
    float aA[8] = {0, 0, 0, 0, 0, 0, 0, 0}, aB[8] = {0, 0, 0, 0, 0, 0, 0, 0};
    float aC[8] = {0, 0, 0, 0, 0, 0, 0, 0}, aD[8] = {0, 0, 0, 0, 0, 0, 0, 0};
    const unsigned short* rb = h1 + sub * 8;
    int e = st;
    for (; e + 7 < end; e += 8) {  // 4 loads -> 8 edges (4 KB in flight)
        int s0 = srclist[e + half];
        int s1 = srclist[e + 2 + half];
        int s2 = srclist[e + 4 + half];
        int s3 = srclist[e + 6 + half];
        uint4 v0 = *(const uint4*)(rb + (size_t)s0 * 256);
        uint4 v1 = *(const uint4*)(rb + (size_t)s1 * 256);
        uint4 v2 = *(const uint4*)(rb + (size_t)s2 * 256);
        uint4 v3 = *(const uint4*)(rb + (size_t)s3 * 256);
        ACC8(aA, v0);
        ACC8(aB, v1);
        ACC8(aC, v2);
        ACC8(aD, v3);
    }
    for (; e + 1 < end; e += 2) {
        int s0 = srclist[e + half];
        uint4 v0 = *(const uint4*)(rb + (size_t)s0 * 256);
        ACC8(aA, v0);
    }
    if (e < end) {  // 1 edge; half==1 contributes 0
        int s0 = srclist[e];
        uint4 v0 = *(const uint4*)(rb + (size_t)s0 * 256);
        if (half == 0) ACC8(aA, v0);
    }
    float inv = 1.f / fmaxf((float)d, 1.f);
    float tot[8];
#pragma unroll
    for (int i = 0; i < 8; ++i) {
        float s = (aA[i] + aB[i]) + (aC[i] + aD[i]);
        s += __shfl_xor(s, 32);
        tot[i] = s * inv;
    }
    if (half == 0) {
        uint4 o;
        o.x = packbf(tot[0], tot[1]);
        o.y = packbf(tot[2], tot[3]);
        o.z = packbf(tot[4], tot[5]);
        o.w = packbf(tot[6], tot[7]);
        *(uint4*)(mean + (size_t)node * 256 + sub * 8) = o;
    }
}

// ======== MFMA GEMM with async A-staging (R6-proven) ========
template <int KH>  // per-half K: 128 (layer1) or 256 (layer2)
__global__ __launch_bounds__(256) void gemm_kernel(
        const bf16_t* __restrict__ A1, const bf16_t* __restrict__ A2,
        const bf16_t* __restrict__ Bt, const float* __restrict__ bias,
        unsigned short* __restrict__ H, int M) {
    constexpr int KT = 2 * KH;
    constexpr int NC = KT / 64;
    constexpr int CPH = KH / 64;
    __shared__ unsigned short As[64 * 64];  // 8 KB
    int t = threadIdx.x, wave = t >> 6, lane = t & 63;
    int quad = lane >> 4, l16 = lane & 15;
    int row0 = blockIdx.x * 64, n0 = wave * 64;

    f32x4 acc[4][4];
#pragma unroll
    for (int i = 0; i < 4; ++i)
#pragma unroll
        for (int j = 0; j < 4; ++j) acc[i][j] = (f32x4)(0.f);

    int rA = wave * 8 + (lane >> 3);
    int kb = lane & 7;
    int kswA = (kb ^ (rA & 7)) << 3;
    unsigned short* ldsA = &As[(size_t)(wave * 8) * 64];
    unsigned short* ldsB = &As[(size_t)(32 + wave * 8) * 64];

    const bf16_t* Bp = Bt + (size_t)(n0 + l16) * KT + quad * 8;

    for (int c = 0; c < NC; ++c) {
        const bf16_t* Ah = (c < CPH) ? A1 : A2;
        int kk = ((c < CPH) ? c : (c - CPH)) * 64;
        gl_lds16(Ah + (size_t)(row0 + rA) * KH + kk + kswA, ldsA);
        gl_lds16(Ah + (size_t)(row0 + 32 + rA) * KH + kk + kswA, ldsB);
        __syncthreads();
        int bk = c * 64;
#pragma unroll
        for (int sub = 0; sub < 2; ++sub) {
            bf16x8 af[4], bfr[4];
#pragma unroll
            for (int mi = 0; mi < 4; ++mi) {
                int r = mi * 16 + l16;
                int qb = sub * 4 + quad;
                af[mi] = *(const bf16x8*)&As[r * 64 + ((qb ^ (r & 7)) << 3)];
            }
#pragma unroll
            for (int ni = 0; ni < 4; ++ni)
                bfr[ni] = *(const bf16x8*)(Bp + (size_t)(ni * 16) * KT + bk + sub * 32);
#pragma unroll
            for (int mi = 0; mi < 4; ++mi)
#pragma unroll
                for (int ni = 0; ni < 4; ++ni)
                    acc[mi][ni] = __builtin_amdgcn_mfma_f32_16x16x32_bf16(
                        af[mi], bfr[ni], acc[mi][ni], 0, 0, 0);
        }
        __syncthreads();
    }

    float bv[4];
#pragma unroll
    for (int ni = 0; ni < 4; ++ni) bv[ni] = bias[n0 + ni * 16 + l16];
#pragma unroll
    for (int mi = 0; mi < 4; ++mi) {
#pragma unroll
        for (int r = 0; r < 4; ++r) {
            int row = row0 + mi * 16 + quad * 4 + r;
            if (row < M) {
#pragma unroll
                for (int ni = 0; ni < 4; ++ni) {
                    int col = n0 + ni * 16 + l16;
                    H[(size_t)row * 256 + col] = f2bf(fmaxf(acc[mi][ni][r] + bv[ni], 0.f));
                }
            }
        }
    }
}

// ---------------- segmented mean pool ----------------
__global__ void pool_kernel(const unsigned short* __restrict__ h2, const int* __restrict__ batch,
                            float* __restrict__ g, float* __restrict__ cnt, int n) {
    int col = threadIdx.x;
    int row0 = blockIdx.x * 256;
    float acc = 0.f;
    int cur = -1, seglen = 0;
    for (int r = 0; r < 256; ++r) {
        int row = row0 + r;
        if (row >= n) break;
        int b = batch[row];
        if (b != cur) {
            if (cur >= 0) {
                atomicAdd(&g[cur * 256 + col], acc);
                if (col == 0) atomicAdd(&cnt[cur], (float)seglen);
            }
            acc = 0.f; cur = b; seglen = 0;
        }
        union { unsigned i; float f; } u;
        u.i = ((unsigned)h2[(size_t)row * 256 + col]) << 16;
        acc += u.f;
        seglen++;
    }
    if (cur >= 0) {
        atomicAdd(&g[cur * 256 + col], acc);
        if (col == 0) atomicAdd(&cnt[cur], (float)seglen);
    }
}

// ---------------- classifier ----------------
__global__ void final_kernel(const float* __restrict__ g, const float* __restrict__ cnt,
                             const float* __restrict__ fcW, const float* __restrict__ fcb,
                             float* __restrict__ out) {
    int t = threadIdx.x;
    for (int o = t; o < NGRAPH * NCLS; o += 256) {
        int gi = o >> 4, c = o & 15;
        float inv = 1.f / fmaxf(cnt[gi], 1.f);
        float dot = 0.f;
        for (int k = 0; k < 256; ++k) dot += g[gi * 256 + k] * fcW[k * 16 + c];
        out[o] = dot * inv + fcb[c];
    }
}

extern "C" void kernel_launch(void* const* d_in, const int* in_sizes, int n_in, void* d_out,
                              int out_size, void* d_ws, size_t ws_size, hipStream_t stream) {
    const float* x   = (const float*)d_in[0];
    const int* edge  = (const int*)d_in[1];
    const int* batch = (const int*)d_in[2];
    const float* W1l = (const float*)d_in[3];
    const float* b1  = (const float*)d_in[4];
    const float* W1r = (const float*)d_in[5];
    const float* W2l = (const float*)d_in[6];
    const float* b2  = (const float*)d_in[7];
    const float* W2r = (const float*)d_in[8];
    const float* fcW = (const float*)d_in[9];
    const float* fcb = (const float*)d_in[10];
    float* out = (float*)d_out;

    const int n = in_sizes[0] / INDIM;   // 100000
    const int E = in_sizes[1] / 2;       // 1600000
    const int* src = edge;
    const int* dst = edge + E;
    const int nbuck = (n + 255) >> 8;    // 391

    char* ws = (char*)d_ws;
    size_t off = 0;
    auto alloc = [&](size_t bytes) {
        size_t p = off;
        off = (off + bytes + 511) & ~(size_t)511;
        return p;
    };
    size_t offs_o    = alloc((size_t)n * 4);
    size_t deg_o     = alloc((size_t)n * 4);          // zeroed
    size_t cnt_o     = alloc(64 * 4);                 // zeroed
    size_t g_o       = alloc(64 * 256 * 4);           // zeroed
    size_t zero_end  = off;
    size_t bsum_o    = alloc(1024 * 4);
    size_t gcur_o    = alloc(512 * 4);
    size_t srclist_o = alloc((size_t)E * 4);
    size_t bt1_o     = alloc(256 * 256 * 2);
    size_t bt2_o     = alloc(256 * 512 * 2);
    size_t xbm2_o    = alloc((size_t)n * 256 * 2);    // xb16 (n*128*2) -> mean2 (n*256*2)
    size_t mean1_o   = alloc((size_t)n * 128 * 2);
    size_t h1_o      = alloc((size_t)n * 256 * 2);
    size_t h2_o      = alloc((size_t)n * 256 * 2);    // tmp (CSR build) aliases here

    int*   offs    = (int*)(ws + offs_o);
    int*   deg     = (int*)(ws + deg_o);
    float* cnt     = (float*)(ws + cnt_o);
    float* g       = (float*)(ws + g_o);
    int*   bsum    = (int*)(ws + bsum_o);
    int*   gcur    = (int*)(ws + gcur_o);
    int*   srclist = (int*)(ws + srclist_o);
    unsigned short* Bt1   = (unsigned short*)(ws + bt1_o);
    unsigned short* Bt2   = (unsigned short*)(ws + bt2_o);
    unsigned short* xb16  = (unsigned short*)(ws + xbm2_o);  // dead after gemm1
    unsigned short* mean2 = (unsigned short*)(ws + xbm2_o);  // written by agg2 (after gemm1)
    unsigned short* mean1 = (unsigned short*)(ws + mean1_o);
    unsigned short* h1b   = (unsigned short*)(ws + h1_o);
    unsigned*       tmp   = (unsigned*)(ws + h2_o);          // dead before gemm2 writes h2
    unsigned short* h2b   = (unsigned short*)(ws + h2_o);

    hipMemsetAsync(ws + deg_o, 0, zero_end - deg_o, stream);

    int eb = (E + 255) / 256;
    int nb = (n + 255) / 256;  // 391
    hist_kernel<<<eb, 256, 0, stream>>>(dst, deg, E);
    scan1_kernel<<<nb, 256, 0, stream>>>(deg, bsum, n);
    scan2_kernel<<<1, 1024, 0, stream>>>(bsum, nb);
    scan3_kernel<<<nb, 256, 0, stream>>>(deg, bsum, offs, gcur, n);
    binA_kernel<<<(E + CHUNK - 1) / CHUNK, 256, 0, stream>>>(src, dst, gcur, tmp, E, nbuck);
    binB_kernel<<<nbuck, 256, 0, stream>>>(tmp, offs, srclist, E, n);

    int castb = n * INDIM / 4 / 256;  // 12500
    prep_kernel<<<castb + 256 + 512, 256, 0, stream>>>(x, xb16, W1l, W1r, Bt1, W2l, W2r, Bt2, castb);

    int aggb = (n * 64 + 255) / 256;
    int gemmb = (n + 63) / 64;  // 1563

    agg1_kernel<<<aggb, 256, 0, stream>>>(xb16, srclist, offs, deg, mean1, n);
    gemm_kernel<128><<<gemmb, 256, 0, stream>>>(
        (const bf16_t*)mean1, (const bf16_t*)xb16, (const bf16_t*)Bt1, b1, h1b, n);
    agg2_kernel<<<aggb, 256, 0, stream>>>(h1b, srclist, offs, deg, mean2, n);
    gemm_kernel<256><<<gemmb, 256, 0, stream>>>(
        (const bf16_t*)mean2, (const bf16_t*)h1b, (const bf16_t*)Bt2, b2, h2b, n);

    pool_kernel<<<nb, 256, 0, stream>>>(h2b, batch, g, cnt, n);
    final_kernel<<<1, 256, 0, stream>>>(g, cnt, fcW, fcb, out);
}